// Round 1
// baseline (544.007 us; speedup 1.0000x reference)
//
#include <hip/hip_runtime.h>
#include <math.h>

#define N 4096
#define E 32
#define NBLK 12
#define D_IN 2240
#define H1 256
#define H2 32
#define NOUT 51
#define MT 8
#define NPAD (N + E*(MT-1))   // 4320
#define NTILE (NPAD/MT)       // 540

__device__ __forceinline__ float gelu(float x){
    return 0.5f * x * (1.0f + erff(x * 0.70710678118654752f));
}

// ---------------- sort rows by expert (single block) ----------------
__global__ void k_sort(const int* __restrict__ desc,
                       int* __restrict__ perm, int* __restrict__ tile_e){
    __shared__ int scnt[E];
    __shared__ int spoff[E+1];
    __shared__ int scur[E];
    int tid = threadIdx.x;
    if (tid < E) scnt[tid] = 0;
    __syncthreads();
    for (int n = tid; n < N; n += blockDim.x) atomicAdd(&scnt[desc[n]], 1);
    __syncthreads();
    if (tid == 0){
        int run = 0;
        for (int e = 0; e < E; e++){ spoff[e] = run; run += ((scnt[e] + MT - 1)/MT)*MT; }
        spoff[E] = run;
    }
    __syncthreads();
    if (tid < E) scur[tid] = spoff[tid];
    for (int p = tid; p < NPAD; p += blockDim.x) perm[p] = -1;
    __syncthreads();
    for (int n = tid; n < N; n += blockDim.x){
        int p = atomicAdd(&scur[desc[n]], 1);
        perm[p] = n;
    }
    for (int t = tid; t < NTILE; t += blockDim.x){
        int p0 = t*MT;
        int e = -1;
        if (p0 < spoff[E]){
            for (int q = 0; q < E; q++){
                if (p0 >= spoff[q] && p0 < spoff[q+1]){ e = q; break; }
            }
        }
        tile_e[t] = e;
    }
}

// ---------------- build feature vector (sorted order) ----------------
__global__ void k_build(const int* __restrict__ perm,
                        const int* __restrict__ piece_idx,
                        const int* __restrict__ side_flag,
                        const int* __restrict__ ep_file,
                        const float* __restrict__ castle_ms,
                        const float* __restrict__ fifty_a,
                        const int* __restrict__ desc_idx,
                        const float* __restrict__ Wp_w, const float* __restrict__ Wp_b,
                        const float* __restrict__ Wc_w, const float* __restrict__ Wc_b,
                        const float* __restrict__ Wep_w, const float* __restrict__ Wep_b,
                        const float* __restrict__ Wf_w, const float* __restrict__ Wf_b,
                        float* __restrict__ xs){
    int pos = blockIdx.x;
    int row = perm[pos];
    float* xr = xs + (size_t)pos * D_IN;
    int tid = threadIdx.x;
    if (row < 0){
        for (int i = tid; i < D_IN; i += blockDim.x) xr[i] = 0.0f;
        return;
    }
    int d = desc_idx[row];
    int s = side_flag[row];
    __shared__ int pidx[64];
    if (tid < 64) pidx[tid] = piece_idx[row*64 + tid];
    __syncthreads();
    const float* Wp  = s ? Wp_b  : Wp_w;
    const float* Wc  = s ? Wc_b  : Wc_w;
    const float* Wep = s ? Wep_b : Wep_w;
    const float* Wf  = s ? Wf_b  : Wf_w;
    int ep  = ep_file[row];
    int epc = ep > 0 ? ep : 0;
    float a = fifty_a[row];
    for (int i = tid; i < D_IN; i += blockDim.x){
        float v;
        if (i < 2048){
            int sq = i >> 5, c = i & 31;
            int pc = pidx[sq];
            float msk = pc >= 0 ? 1.0f : 0.0f;
            int pcc = pc > 0 ? pc : 0;
            v = Wp[(((size_t)d*64 + sq)*12 + pcc)*32 + c] * msk;
        } else if (i < 2176){
            int j = i - 2048; int ci = j >> 5, c = j & 31;
            v = castle_ms[row*4 + ci] * Wc[((size_t)d*4 + ci)*32 + c];
        } else if (i < 2208){
            int c = i - 2176;
            float msk = ep >= 0 ? 1.0f : 0.0f;
            v = Wep[((size_t)d*8 + epc)*32 + c] * msk;
        } else {
            int c = i - 2208;
            v = (1.0f - a) * Wf[(size_t)d*64 + c] + a * Wf[(size_t)d*64 + 32 + c];
        }
        xr[i] = v;
    }
}

// ---------------- fc1: [8 x 2240] @ [2240 x 256] + gelu + LN ----------------
__launch_bounds__(256)
__global__ void k_fc1(const int* __restrict__ tile_e,
                      const float* __restrict__ xs,
                      const float* __restrict__ W1, const float* __restrict__ b1,
                      const float* __restrict__ g1, const float* __restrict__ be1,
                      float* __restrict__ h1){
    int t = blockIdx.x;
    int e = tile_e[t];
    if (e < 0) return;
    int c = threadIdx.x;
    const float* W = W1 + (size_t)e * D_IN * H1;
    const float* X = xs + (size_t)t * MT * D_IN;
    float acc[MT];
    #pragma unroll
    for (int m = 0; m < MT; m++) acc[m] = 0.0f;
    for (int k = 0; k < D_IN; k += 4){
        float w0 = W[(size_t)(k+0)*H1 + c];
        float w1 = W[(size_t)(k+1)*H1 + c];
        float w2 = W[(size_t)(k+2)*H1 + c];
        float w3 = W[(size_t)(k+3)*H1 + c];
        #pragma unroll
        for (int m = 0; m < MT; m++){
            float4 xv = *(const float4*)(X + m*D_IN + k);  // block-uniform -> s_load
            acc[m] = fmaf(xv.x, w0, acc[m]);
            acc[m] = fmaf(xv.y, w1, acc[m]);
            acc[m] = fmaf(xv.z, w2, acc[m]);
            acc[m] = fmaf(xv.w, w3, acc[m]);
        }
    }
    float bias = b1[e*H1 + c];
    float gg = g1[e*H1 + c], bb = be1[e*H1 + c];
    float y[MT];
    #pragma unroll
    for (int m = 0; m < MT; m++) y[m] = gelu(acc[m] + bias);
    __shared__ float red[2][MT][4];
    int wid = c >> 6, lane = c & 63;
    #pragma unroll
    for (int m = 0; m < MT; m++){
        float v = y[m];
        for (int o = 32; o > 0; o >>= 1) v += __shfl_xor(v, o);
        if (lane == 0) red[0][m][wid] = v;
    }
    __syncthreads();
    float mean[MT];
    #pragma unroll
    for (int m = 0; m < MT; m++)
        mean[m] = (red[0][m][0] + red[0][m][1] + red[0][m][2] + red[0][m][3]) * (1.0f/H1);
    #pragma unroll
    for (int m = 0; m < MT; m++){
        float dv = y[m] - mean[m];
        float v = dv*dv;
        for (int o = 32; o > 0; o >>= 1) v += __shfl_xor(v, o);
        if (lane == 0) red[1][m][wid] = v;
    }
    __syncthreads();
    #pragma unroll
    for (int m = 0; m < MT; m++){
        float var = (red[1][m][0] + red[1][m][1] + red[1][m][2] + red[1][m][3]) * (1.0f/H1);
        float out = (y[m] - mean[m]) * rsqrtf(var + 1e-5f) * gg + bb;
        h1[(size_t)(t*MT + m)*H1 + c] = out;
    }
}

// ---------------- fc2: [8 x 256] @ [256 x 32] + gelu + LN ----------------
__global__ void k_fc2(const int* __restrict__ tile_e,
                      const float* __restrict__ h1,
                      const float* __restrict__ W2, const float* __restrict__ b2,
                      const float* __restrict__ g2, const float* __restrict__ be2,
                      float* __restrict__ h){
    int t = blockIdx.x;
    int e = tile_e[t];
    if (e < 0) return;
    int m = threadIdx.x >> 5, c = threadIdx.x & 31;
    int pos = t*MT + m;
    const float* hr = h1 + (size_t)pos * H1;
    const float* W = W2 + (size_t)e * H1 * H2;
    float acc = b2[e*H2 + c];
    for (int k = 0; k < H1; k += 4){
        float4 hv = *(const float4*)(hr + k);
        acc = fmaf(hv.x, W[(k+0)*H2 + c], acc);
        acc = fmaf(hv.y, W[(k+1)*H2 + c], acc);
        acc = fmaf(hv.z, W[(k+2)*H2 + c], acc);
        acc = fmaf(hv.w, W[(k+3)*H2 + c], acc);
    }
    float y = gelu(acc);
    float s = y;
    for (int o = 16; o > 0; o >>= 1) s += __shfl_xor(s, o);
    float mean = s * (1.0f/H2);
    float dv = y - mean;
    float v = dv*dv;
    for (int o = 16; o > 0; o >>= 1) v += __shfl_xor(v, o);
    float var = v * (1.0f/H2);
    float out = dv * rsqrtf(var + 1e-5f) * g2[e*H2+c] + be2[e*H2+c];
    h[(size_t)pos*H2 + c] = out;
}

// ---------------- 12 fused residual blocks ----------------
__global__ void k_blocks(const int* __restrict__ tile_e,
                         const float* __restrict__ Aw, const float* __restrict__ Ab,
                         const float* __restrict__ Ag, const float* __restrict__ Abe,
                         const float* __restrict__ Bw, const float* __restrict__ Bb,
                         const float* __restrict__ Bg, const float* __restrict__ Bbe,
                         float* __restrict__ h){
    int t = blockIdx.x;
    int e = tile_e[t];
    if (e < 0) return;
    int m = threadIdx.x >> 5, c = threadIdx.x & 31;
    int pos = t*MT + m;
    float hv = h[(size_t)pos*H2 + c];
    __shared__ float sA[1024], sB[1024], sh[MT][33];
    for (int tb = 0; tb < NBLK; tb++){
        const float* A = Aw + ((size_t)tb*E + e)*1024;
        const float* B = Bw + ((size_t)tb*E + e)*1024;
        __syncthreads();
        for (int i = threadIdx.x; i < 1024; i += 256){ sA[i] = A[i]; sB[i] = B[i]; }
        sh[m][c] = hv;
        __syncthreads();
        float acc = Ab[((size_t)tb*E + e)*32 + c];
        #pragma unroll
        for (int k = 0; k < 32; k++) acc = fmaf(sh[m][k], sA[k*32 + c], acc);
        float y = gelu(acc);
        float s = y;
        for (int o = 16; o > 0; o >>= 1) s += __shfl_xor(s, o);
        float mean = s * (1.0f/32);
        float dv = y - mean;
        float v = dv*dv;
        for (int o = 16; o > 0; o >>= 1) v += __shfl_xor(v, o);
        float var = v * (1.0f/32);
        y = dv * rsqrtf(var + 1e-5f) * Ag[((size_t)tb*E+e)*32+c] + Abe[((size_t)tb*E+e)*32+c];
        __syncthreads();
        sh[m][c] = y;
        __syncthreads();
        acc = Bb[((size_t)tb*E + e)*32 + c];
        #pragma unroll
        for (int k = 0; k < 32; k++) acc = fmaf(sh[m][k], sB[k*32 + c], acc);
        y = gelu(acc);
        s = y;
        for (int o = 16; o > 0; o >>= 1) s += __shfl_xor(s, o);
        mean = s * (1.0f/32);
        dv = y - mean;
        v = dv*dv;
        for (int o = 16; o > 0; o >>= 1) v += __shfl_xor(v, o);
        var = v * (1.0f/32);
        y = dv * rsqrtf(var + 1e-5f) * Bg[((size_t)tb*E+e)*32+c] + Bbe[((size_t)tb*E+e)*32+c];
        hv += y;
    }
    h[(size_t)pos*H2 + c] = hv;
}

// ---------------- out proj + softmax + p_win (one wave per row) ----------------
__global__ void k_out(const int* __restrict__ perm, const int* __restrict__ tile_e,
                      const float* __restrict__ h,
                      const float* __restrict__ Ow, const float* __restrict__ Ob,
                      const float* __restrict__ bins,
                      float* __restrict__ out){
    int wid = threadIdx.x >> 6, lane = threadIdx.x & 63;
    int pos = blockIdx.x*4 + wid;
    if (pos >= NPAD) return;
    int row = perm[pos];
    if (row < 0) return;
    int e = tile_e[pos >> 3];
    float gv = 0.0f;
    if (lane < 32) gv = gelu(h[(size_t)pos*H2 + lane]);
    float acc = (lane < NOUT) ? Ob[e*NOUT + lane] : -INFINITY;
    const float* W = Ow + (size_t)e*32*NOUT;
    #pragma unroll
    for (int k = 0; k < 32; k++){
        float gk = __shfl(gv, k);
        if (lane < NOUT) acc = fmaf(gk, W[k*NOUT + lane], acc);
    }
    if (lane < NOUT) out[(size_t)row*NOUT + lane] = acc;
    float mx = acc;
    for (int o = 32; o > 0; o >>= 1) mx = fmaxf(mx, __shfl_xor(mx, o));
    float p = (lane < NOUT) ? expf(acc - mx) : 0.0f;
    float sum = p;
    for (int o = 32; o > 0; o >>= 1) sum += __shfl_xor(sum, o);
    float pb = (lane < NOUT) ? p * bins[lane] : 0.0f;
    float sb = pb;
    for (int o = 32; o > 0; o >>= 1) sb += __shfl_xor(sb, o);
    if (lane == 0) out[(size_t)N*NOUT + row] = sb / sum;
}

extern "C" void kernel_launch(void* const* d_in, const int* in_sizes, int n_in,
                              void* d_out, int out_size, void* d_ws, size_t ws_size,
                              hipStream_t stream){
    const int*   piece_idx = (const int*)d_in[0];
    const int*   side_flag = (const int*)d_in[1];
    const int*   ep_file   = (const int*)d_in[2];
    const float* castle_ms = (const float*)d_in[3];
    const float* fifty_a   = (const float*)d_in[4];
    const int*   desc      = (const int*)d_in[5];
    const float* Wp_w  = (const float*)d_in[6];
    const float* Wp_b  = (const float*)d_in[7];
    const float* Wc_w  = (const float*)d_in[8];
    const float* Wc_b  = (const float*)d_in[9];
    const float* Wep_w = (const float*)d_in[10];
    const float* Wep_b = (const float*)d_in[11];
    const float* Wf_w  = (const float*)d_in[12];
    const float* Wf_b  = (const float*)d_in[13];
    const float* fc1_w = (const float*)d_in[14];
    const float* fc1_b = (const float*)d_in[15];
    const float* ln1_g = (const float*)d_in[16];
    const float* ln1_b = (const float*)d_in[17];
    const float* fc2_w = (const float*)d_in[18];
    const float* fc2_b = (const float*)d_in[19];
    const float* ln2_g = (const float*)d_in[20];
    const float* ln2_b = (const float*)d_in[21];
    const float* blkA_w  = (const float*)d_in[22];
    const float* blkA_b  = (const float*)d_in[23];
    const float* blkA_g  = (const float*)d_in[24];
    const float* blkA_be = (const float*)d_in[25];
    const float* blkB_w  = (const float*)d_in[26];
    const float* blkB_b  = (const float*)d_in[27];
    const float* blkB_g  = (const float*)d_in[28];
    const float* blkB_be = (const float*)d_in[29];
    const float* out_w = (const float*)d_in[30];
    const float* out_b = (const float*)d_in[31];
    const float* bins  = (const float*)d_in[32];

    char* wsp = (char*)d_ws;
    auto alloc = [&](size_t bytes){ void* p = (void*)wsp; wsp += (bytes + 255) & ~(size_t)255; return p; };
    int*   perm   = (int*)  alloc((size_t)NPAD*4);
    int*   tile_e = (int*)  alloc((size_t)NTILE*4);
    float* xs     = (float*)alloc((size_t)NPAD*D_IN*4);
    float* h1     = (float*)alloc((size_t)NPAD*H1*4);
    float* h      = (float*)alloc((size_t)NPAD*H2*4);

    k_sort<<<1, 256, 0, stream>>>(desc, perm, tile_e);
    k_build<<<NPAD, 256, 0, stream>>>(perm, piece_idx, side_flag, ep_file, castle_ms,
                                      fifty_a, desc, Wp_w, Wp_b, Wc_w, Wc_b,
                                      Wep_w, Wep_b, Wf_w, Wf_b, xs);
    k_fc1<<<NTILE, 256, 0, stream>>>(tile_e, xs, fc1_w, fc1_b, ln1_g, ln1_b, h1);
    k_fc2<<<NTILE, 256, 0, stream>>>(tile_e, h1, fc2_w, fc2_b, ln2_g, ln2_b, h);
    k_blocks<<<NTILE, 256, 0, stream>>>(tile_e, blkA_w, blkA_b, blkA_g, blkA_be,
                                        blkB_w, blkB_b, blkB_g, blkB_be, h);
    k_out<<<NPAD/4, 256, 0, stream>>>(perm, tile_e, h, out_w, out_b, bins, (float*)d_out);
}

// Round 2
// 382.260 us; speedup vs baseline: 1.4231x; 1.4231x over previous
//
#include <hip/hip_runtime.h>
#include <math.h>

#define N 4096
#define E 32
#define NBLK 12
#define D_IN 2240
#define H1 256
#define H2 32
#define NOUT 51
#define MT 16
#define NPAD (N + E*(MT-1))   // 4576
#define NTILE (NPAD/MT)       // 286
#define KSTEPS (D_IN/32)      // 70

typedef short s8v __attribute__((ext_vector_type(8)));
typedef float f4v __attribute__((ext_vector_type(4)));

__device__ __forceinline__ float gelu(float x){
    return 0.5f * x * (1.0f + erff(x * 0.70710678118654752f));
}
__device__ __forceinline__ unsigned short f2bf(float f){
    unsigned int u = __float_as_uint(f);
    unsigned int r = (u + 0x7fffu + ((u >> 16) & 1u)) >> 16;
    return (unsigned short)r;
}

// ---------------- sort rows by expert (single block) ----------------
__global__ void k_sort(const int* __restrict__ desc,
                       int* __restrict__ perm, int* __restrict__ tile_e){
    __shared__ int scnt[E];
    __shared__ int spoff[E+1];
    __shared__ int scur[E];
    int tid = threadIdx.x;
    if (tid < E) scnt[tid] = 0;
    __syncthreads();
    for (int n = tid; n < N; n += blockDim.x) atomicAdd(&scnt[desc[n]], 1);
    __syncthreads();
    if (tid == 0){
        int run = 0;
        for (int e = 0; e < E; e++){ spoff[e] = run; run += ((scnt[e] + MT - 1)/MT)*MT; }
        spoff[E] = run;
    }
    __syncthreads();
    if (tid < E) scur[tid] = spoff[tid];
    for (int p = tid; p < NPAD; p += blockDim.x) perm[p] = -1;
    __syncthreads();
    for (int n = tid; n < N; n += blockDim.x){
        int p = atomicAdd(&scur[desc[n]], 1);
        perm[p] = n;
    }
    for (int t = tid; t < NTILE; t += blockDim.x){
        int p0 = t*MT;
        int e = -1;
        if (p0 < spoff[E]){
            for (int q = 0; q < E; q++){
                if (p0 >= spoff[q] && p0 < spoff[q+1]){ e = q; break; }
            }
        }
        tile_e[t] = e;
    }
}

// ---------------- convert fc1_w (E,2240,256) f32 -> Wt (E,256,2240) bf16 ----------------
__global__ void k_convert(const float* __restrict__ W1, unsigned short* __restrict__ Wt){
    int kt = blockIdx.x;          // 0..69
    int e  = blockIdx.y;          // 0..31
    int n  = threadIdx.x;         // 0..255
    const float* src = W1 + (size_t)e*D_IN*H1 + (size_t)kt*32*H1 + n;
    unsigned short* dst = Wt + ((size_t)e*H1 + n)*D_IN + kt*32;
    #pragma unroll
    for (int ch = 0; ch < 4; ch++){
        s8v p;
        #pragma unroll
        for (int j = 0; j < 8; j++) p[j] = (short)f2bf(src[(ch*8 + j)*H1]);
        *(s8v*)(dst + ch*8) = p;
    }
}

// ---------------- build feature vector (sorted order, bf16) ----------------
__global__ void k_build(const int* __restrict__ perm,
                        const int* __restrict__ piece_idx,
                        const int* __restrict__ side_flag,
                        const int* __restrict__ ep_file,
                        const float* __restrict__ castle_ms,
                        const float* __restrict__ fifty_a,
                        const int* __restrict__ desc_idx,
                        const float* __restrict__ Wp_w, const float* __restrict__ Wp_b,
                        const float* __restrict__ Wc_w, const float* __restrict__ Wc_b,
                        const float* __restrict__ Wep_w, const float* __restrict__ Wep_b,
                        const float* __restrict__ Wf_w, const float* __restrict__ Wf_b,
                        unsigned short* __restrict__ xs){
    int pos = blockIdx.x;
    int row = perm[pos];
    unsigned short* xr = xs + (size_t)pos * D_IN;
    int tid = threadIdx.x;
    if (row < 0){
        for (int i = tid; i < D_IN; i += blockDim.x) xr[i] = 0;
        return;
    }
    int d = desc_idx[row];
    int s = side_flag[row];
    __shared__ int pidx[64];
    if (tid < 64) pidx[tid] = piece_idx[row*64 + tid];
    __syncthreads();
    const float* Wp  = s ? Wp_b  : Wp_w;
    const float* Wc  = s ? Wc_b  : Wc_w;
    const float* Wep = s ? Wep_b : Wep_w;
    const float* Wf  = s ? Wf_b  : Wf_w;
    int ep  = ep_file[row];
    int epc = ep > 0 ? ep : 0;
    float a = fifty_a[row];
    for (int i = tid; i < D_IN; i += blockDim.x){
        float v;
        if (i < 2048){
            int sq = i >> 5, c = i & 31;
            int pc = pidx[sq];
            float msk = pc >= 0 ? 1.0f : 0.0f;
            int pcc = pc > 0 ? pc : 0;
            v = Wp[(((size_t)d*64 + sq)*12 + pcc)*32 + c] * msk;
        } else if (i < 2176){
            int j = i - 2048; int ci = j >> 5, c = j & 31;
            v = castle_ms[row*4 + ci] * Wc[((size_t)d*4 + ci)*32 + c];
        } else if (i < 2208){
            int c = i - 2176;
            float msk = ep >= 0 ? 1.0f : 0.0f;
            v = Wep[((size_t)d*8 + epc)*32 + c] * msk;
        } else {
            int c = i - 2208;
            v = (1.0f - a) * Wf[(size_t)d*64 + c] + a * Wf[(size_t)d*64 + 32 + c];
        }
        xr[i] = f2bf(v);
    }
}

// ---------------- fc1 MFMA: [16 x 2240] @ [2240 x 256], writes gelu(acc+bias) ----------------
__launch_bounds__(256)
__global__ void k_fc1(const int* __restrict__ tile_e,
                      const unsigned short* __restrict__ xs,
                      const unsigned short* __restrict__ Wt,
                      const float* __restrict__ b1,
                      float* __restrict__ h1){
    int t = blockIdx.x;
    int half = blockIdx.y;      // 0..1, 128 cols each
    int e = tile_e[t];
    if (e < 0) return;
    int lane = threadIdx.x & 63, wave = threadIdx.x >> 6;
    int quad = lane >> 4, l16 = lane & 15;
    const s8v* A  = (const s8v*)(xs + (size_t)(t*MT + l16)*D_IN + quad*8);
    int n0 = half*128 + wave*32 + l16;
    const s8v* B0 = (const s8v*)(Wt + ((size_t)e*H1 + n0)*D_IN + quad*8);
    const s8v* B1 = (const s8v*)(Wt + ((size_t)e*H1 + n0 + 16)*D_IN + quad*8);
    f4v acc0 = {0.f,0.f,0.f,0.f}, acc1 = {0.f,0.f,0.f,0.f};
    #pragma unroll 2
    for (int k = 0; k < KSTEPS; k++){
        s8v a  = A[k*4];
        s8v b0 = B0[k*4];
        s8v b1v= B1[k*4];
        acc0 = __builtin_amdgcn_mfma_f32_16x16x32_bf16(a, b0, acc0, 0, 0, 0);
        acc1 = __builtin_amdgcn_mfma_f32_16x16x32_bf16(a, b1v, acc1, 0, 0, 0);
    }
    // C layout: col = lane&15, row = quad*4 + reg
    int col0 = half*128 + wave*32 + l16;
    float bb0 = b1[e*H1 + col0];
    float bb1 = b1[e*H1 + col0 + 16];
    #pragma unroll
    for (int r = 0; r < 4; r++){
        int pos = t*MT + quad*4 + r;
        h1[(size_t)pos*H1 + col0]      = gelu(acc0[r] + bb0);
        h1[(size_t)pos*H1 + col0 + 16] = gelu(acc1[r] + bb1);
    }
}

// ---------------- fc2 (+fused LN1 in, LN2 out): [16 x 256] @ [256 x 32] ----------------
__launch_bounds__(512)
__global__ void k_fc2(const int* __restrict__ tile_e,
                      const float* __restrict__ h1,
                      const float* __restrict__ g1, const float* __restrict__ be1,
                      const float* __restrict__ W2, const float* __restrict__ b2,
                      const float* __restrict__ g2, const float* __restrict__ be2,
                      float* __restrict__ h){
    int t = blockIdx.x;
    int e = tile_e[t];
    if (e < 0) return;
    __shared__ float sh[MT][H1+1];
    for (int i = threadIdx.x; i < MT*H1/4; i += 512){
        int r = i >> 6, cc = (i & 63) << 2;
        float4 v = *(const float4*)(h1 + (size_t)(t*MT + r)*H1 + cc);
        sh[r][cc] = v.x; sh[r][cc+1] = v.y; sh[r][cc+2] = v.z; sh[r][cc+3] = v.w;
    }
    __syncthreads();
    int m = threadIdx.x >> 5, c = threadIdx.x & 31;
    float s = 0.f;
    for (int k = c; k < H1; k += 32) s += sh[m][k];
    for (int o = 16; o > 0; o >>= 1) s += __shfl_xor(s, o);
    float mean = s * (1.0f/H1);
    float v2 = 0.f;
    for (int k = c; k < H1; k += 32){ float d = sh[m][k] - mean; v2 += d*d; }
    for (int o = 16; o > 0; o >>= 1) v2 += __shfl_xor(v2, o);
    float rs = rsqrtf(v2 * (1.0f/H1) + 1e-5f);
    const float* g1e  = g1  + e*H1;
    const float* be1e = be1 + e*H1;
    const float* W = W2 + (size_t)e*H1*H2;
    float acc = b2[e*H2 + c];
    for (int k = 0; k < H1; k++){
        float hn = (sh[m][k] - mean) * rs * g1e[k] + be1e[k];
        acc = fmaf(hn, W[k*H2 + c], acc);
    }
    float y = gelu(acc);
    float ss = y;
    for (int o = 16; o > 0; o >>= 1) ss += __shfl_xor(ss, o);
    float mean2 = ss * (1.0f/H2);
    float dv = y - mean2;
    float vv = dv*dv;
    for (int o = 16; o > 0; o >>= 1) vv += __shfl_xor(vv, o);
    float var2 = vv * (1.0f/H2);
    float out = dv * rsqrtf(var2 + 1e-5f) * g2[e*H2+c] + be2[e*H2+c];
    h[(size_t)(t*MT + m)*H2 + c] = out;
}

// ---------------- 12 fused residual blocks ----------------
__launch_bounds__(512)
__global__ void k_blocks(const int* __restrict__ tile_e,
                         const float* __restrict__ Aw, const float* __restrict__ Ab,
                         const float* __restrict__ Ag, const float* __restrict__ Abe,
                         const float* __restrict__ Bw, const float* __restrict__ Bb,
                         const float* __restrict__ Bg, const float* __restrict__ Bbe,
                         float* __restrict__ h){
    int t = blockIdx.x;
    int e = tile_e[t];
    if (e < 0) return;
    int m = threadIdx.x >> 5, c = threadIdx.x & 31;
    int pos = t*MT + m;
    float hv = h[(size_t)pos*H2 + c];
    __shared__ float sA[1024], sB[1024], shh[MT][33];
    for (int tb = 0; tb < NBLK; tb++){
        const float* A = Aw + ((size_t)tb*E + e)*1024;
        const float* B = Bw + ((size_t)tb*E + e)*1024;
        __syncthreads();
        for (int i = threadIdx.x; i < 1024; i += 512){ sA[i] = A[i]; sB[i] = B[i]; }
        shh[m][c] = hv;
        __syncthreads();
        float acc = Ab[((size_t)tb*E + e)*32 + c];
        #pragma unroll
        for (int k = 0; k < 32; k++) acc = fmaf(shh[m][k], sA[k*32 + c], acc);
        float y = gelu(acc);
        float s = y;
        for (int o = 16; o > 0; o >>= 1) s += __shfl_xor(s, o);
        float mean = s * (1.0f/32);
        float dv = y - mean;
        float v = dv*dv;
        for (int o = 16; o > 0; o >>= 1) v += __shfl_xor(v, o);
        float var = v * (1.0f/32);
        y = dv * rsqrtf(var + 1e-5f) * Ag[((size_t)tb*E+e)*32+c] + Abe[((size_t)tb*E+e)*32+c];
        __syncthreads();
        shh[m][c] = y;
        __syncthreads();
        acc = Bb[((size_t)tb*E + e)*32 + c];
        #pragma unroll
        for (int k = 0; k < 32; k++) acc = fmaf(shh[m][k], sB[k*32 + c], acc);
        y = gelu(acc);
        s = y;
        for (int o = 16; o > 0; o >>= 1) s += __shfl_xor(s, o);
        mean = s * (1.0f/32);
        dv = y - mean;
        v = dv*dv;
        for (int o = 16; o > 0; o >>= 1) v += __shfl_xor(v, o);
        var = v * (1.0f/32);
        y = dv * rsqrtf(var + 1e-5f) * Bg[((size_t)tb*E+e)*32+c] + Bbe[((size_t)tb*E+e)*32+c];
        hv += y;
    }
    h[(size_t)pos*H2 + c] = hv;
}

// ---------------- out proj + softmax + p_win (one wave per row) ----------------
__global__ void k_out(const int* __restrict__ perm, const int* __restrict__ tile_e,
                      const float* __restrict__ h,
                      const float* __restrict__ Ow, const float* __restrict__ Ob,
                      const float* __restrict__ bins,
                      float* __restrict__ out){
    int wid = threadIdx.x >> 6, lane = threadIdx.x & 63;
    int pos = blockIdx.x*4 + wid;
    if (pos >= NPAD) return;
    int row = perm[pos];
    if (row < 0) return;
    int e = tile_e[pos / MT];
    float gv = 0.0f;
    if (lane < 32) gv = gelu(h[(size_t)pos*H2 + lane]);
    float acc = (lane < NOUT) ? Ob[e*NOUT + lane] : -INFINITY;
    const float* W = Ow + (size_t)e*32*NOUT;
    #pragma unroll
    for (int k = 0; k < 32; k++){
        float gk = __shfl(gv, k);
        if (lane < NOUT) acc = fmaf(gk, W[k*NOUT + lane], acc);
    }
    if (lane < NOUT) out[(size_t)row*NOUT + lane] = acc;
    float mx = acc;
    for (int o = 32; o > 0; o >>= 1) mx = fmaxf(mx, __shfl_xor(mx, o));
    float p = (lane < NOUT) ? expf(acc - mx) : 0.0f;
    float sum = p;
    for (int o = 32; o > 0; o >>= 1) sum += __shfl_xor(sum, o);
    float pb = (lane < NOUT) ? p * bins[lane] : 0.0f;
    float sb = pb;
    for (int o = 32; o > 0; o >>= 1) sb += __shfl_xor(sb, o);
    if (lane == 0) out[(size_t)N*NOUT + row] = sb / sum;
}

extern "C" void kernel_launch(void* const* d_in, const int* in_sizes, int n_in,
                              void* d_out, int out_size, void* d_ws, size_t ws_size,
                              hipStream_t stream){
    const int*   piece_idx = (const int*)d_in[0];
    const int*   side_flag = (const int*)d_in[1];
    const int*   ep_file   = (const int*)d_in[2];
    const float* castle_ms = (const float*)d_in[3];
    const float* fifty_a   = (const float*)d_in[4];
    const int*   desc      = (const int*)d_in[5];
    const float* Wp_w  = (const float*)d_in[6];
    const float* Wp_b  = (const float*)d_in[7];
    const float* Wc_w  = (const float*)d_in[8];
    const float* Wc_b  = (const float*)d_in[9];
    const float* Wep_w = (const float*)d_in[10];
    const float* Wep_b = (const float*)d_in[11];
    const float* Wf_w  = (const float*)d_in[12];
    const float* Wf_b  = (const float*)d_in[13];
    const float* fc1_w = (const float*)d_in[14];
    const float* fc1_b = (const float*)d_in[15];
    const float* ln1_g = (const float*)d_in[16];
    const float* ln1_b = (const float*)d_in[17];
    const float* fc2_w = (const float*)d_in[18];
    const float* fc2_b = (const float*)d_in[19];
    const float* ln2_g = (const float*)d_in[20];
    const float* ln2_b = (const float*)d_in[21];
    const float* blkA_w  = (const float*)d_in[22];
    const float* blkA_b  = (const float*)d_in[23];
    const float* blkA_g  = (const float*)d_in[24];
    const float* blkA_be = (const float*)d_in[25];
    const float* blkB_w  = (const float*)d_in[26];
    const float* blkB_b  = (const float*)d_in[27];
    const float* blkB_g  = (const float*)d_in[28];
    const float* blkB_be = (const float*)d_in[29];
    const float* out_w = (const float*)d_in[30];
    const float* out_b = (const float*)d_in[31];
    const float* bins  = (const float*)d_in[32];

    char* wsp = (char*)d_ws;
    auto alloc = [&](size_t bytes){ void* p = (void*)wsp; wsp += (bytes + 255) & ~(size_t)255; return p; };
    int*            perm   = (int*)            alloc((size_t)NPAD*4);
    int*            tile_e = (int*)            alloc((size_t)NTILE*4);
    unsigned short* Wt     = (unsigned short*) alloc((size_t)E*H1*D_IN*2);
    unsigned short* xs     = (unsigned short*) alloc((size_t)NPAD*D_IN*2);
    float*          h1     = (float*)          alloc((size_t)NPAD*H1*4);
    float*          h      = (float*)          alloc((size_t)NPAD*H2*4);

    k_sort<<<1, 256, 0, stream>>>(desc, perm, tile_e);
    k_convert<<<dim3(KSTEPS, E), 256, 0, stream>>>(fc1_w, Wt);
    k_build<<<NPAD, 256, 0, stream>>>(perm, piece_idx, side_flag, ep_file, castle_ms,
                                      fifty_a, desc, Wp_w, Wp_b, Wc_w, Wc_b,
                                      Wep_w, Wep_b, Wf_w, Wf_b, xs);
    k_fc1<<<dim3(NTILE, 2), 256, 0, stream>>>(tile_e, xs, Wt, fc1_b, h1);
    k_fc2<<<NTILE, 512, 0, stream>>>(tile_e, h1, ln1_g, ln1_b, fc2_w, fc2_b, ln2_g, ln2_b, h);
    k_blocks<<<NTILE, 512, 0, stream>>>(tile_e, blkA_w, blkA_b, blkA_g, blkA_be,
                                        blkB_w, blkB_b, blkB_g, blkB_be, h);
    k_out<<<(NPAD + 3)/4, 256, 0, stream>>>(perm, tile_e, h, out_w, out_b, bins, (float*)d_out);
}

// Round 3
// 330.355 us; speedup vs baseline: 1.6467x; 1.1571x over previous
//
#include <hip/hip_runtime.h>
#include <math.h>

#define N 4096
#define E 32
#define NBLK 12
#define D_IN 2240
#define H1 256
#define H2 32
#define NOUT 51
#define MT 16
#define NPAD (N + E*(MT-1))   // 4576
#define NTILE (NPAD/MT)       // 286
#define KSTEPS (D_IN/32)      // 70
#define KSPLIT 4
#define NROWS 4608
#define GMAX 96

typedef short s8v __attribute__((ext_vector_type(8)));
typedef float f4v __attribute__((ext_vector_type(4)));

__device__ __forceinline__ float gelu(float x){
    return 0.5f * x * (1.0f + erff(x * 0.70710678118654752f));
}
__device__ __forceinline__ unsigned short f2bf(float f){
    unsigned int u = __float_as_uint(f);
    unsigned int r = (u + 0x7fffu + ((u >> 16) & 1u)) >> 16;
    return (unsigned short)r;
}

// ---------------- sort rows by expert + build 8-tile groups ----------------
__global__ void k_sort(const int* __restrict__ desc,
                       int* __restrict__ perm, int* __restrict__ tile_e,
                       int4* __restrict__ garr, int* __restrict__ ngroups){
    __shared__ int scnt[E];
    __shared__ int spoff[E+1];
    __shared__ int scur[E];
    int tid = threadIdx.x;
    if (tid < E) scnt[tid] = 0;
    __syncthreads();
    for (int n = tid; n < N; n += blockDim.x) atomicAdd(&scnt[desc[n]], 1);
    __syncthreads();
    if (tid == 0){
        int run = 0;
        for (int e = 0; e < E; e++){ spoff[e] = run; run += ((scnt[e] + MT - 1)/MT)*MT; }
        spoff[E] = run;
        int ng = 0;
        for (int e = 0; e < E; e++){
            int t0 = spoff[e]/MT, t1 = spoff[e+1]/MT;
            for (int t = t0; t < t1; t += 8){
                int nv = t1 - t; if (nv > 8) nv = 8;
                if (ng < GMAX) garr[ng] = make_int4(t, e, nv, 0);
                ng++;
            }
        }
        *ngroups = (ng > GMAX) ? GMAX : ng;
    }
    __syncthreads();
    if (tid < E) scur[tid] = spoff[tid];
    for (int p = tid; p < NPAD; p += blockDim.x) perm[p] = -1;
    __syncthreads();
    for (int n = tid; n < N; n += blockDim.x){
        int p = atomicAdd(&scur[desc[n]], 1);
        perm[p] = n;
    }
    for (int t = tid; t < NTILE; t += blockDim.x){
        int p0 = t*MT;
        int e = -1;
        if (p0 < spoff[E]){
            for (int q = 0; q < E; q++){
                if (p0 >= spoff[q] && p0 < spoff[q+1]){ e = q; break; }
            }
        }
        tile_e[t] = e;
    }
}

// ------- convert fc1_w (E,2240,256) f32 -> Wt (E,256,2240) bf16, LDS transpose -------
__global__ void k_convert(const float* __restrict__ W1, unsigned short* __restrict__ Wt){
    int kt = blockIdx.x;   // 0..34, 64 k each
    int nt = blockIdx.y;   // 0..3,  64 n each
    int e  = blockIdx.z;
    __shared__ float lds[64][65];
    int t = threadIdx.x;
    int k0 = kt*64, n0 = nt*64;
    int kk = t >> 4, nn = (t & 15) * 4;
    const float* src = W1 + ((size_t)e*D_IN + k0)*H1 + n0;
    #pragma unroll
    for (int r = 0; r < 4; r++){
        float4 v = *(const float4*)(src + (size_t)(kk + r*16)*H1 + nn);
        lds[kk + r*16][nn]   = v.x;
        lds[kk + r*16][nn+1] = v.y;
        lds[kk + r*16][nn+2] = v.z;
        lds[kk + r*16][nn+3] = v.w;
    }
    __syncthreads();
    int n = t >> 2, kq = t & 3;
    s8v p0, p1;
    #pragma unroll
    for (int j = 0; j < 8; j++) p0[j] = (short)f2bf(lds[kq*16 + j][n]);
    #pragma unroll
    for (int j = 0; j < 8; j++) p1[j] = (short)f2bf(lds[kq*16 + 8 + j][n]);
    unsigned short* dst = Wt + ((size_t)(e*H1 + n0 + n))*D_IN + k0 + kq*16;
    *(s8v*)dst       = p0;
    *(s8v*)(dst + 8) = p1;
}

// ---------------- build feature vector (sorted order, bf16, vectorized) ----------------
__global__ void k_build(const int* __restrict__ perm,
                        const int* __restrict__ piece_idx,
                        const int* __restrict__ side_flag,
                        const int* __restrict__ ep_file,
                        const float* __restrict__ castle_ms,
                        const float* __restrict__ fifty_a,
                        const int* __restrict__ desc_idx,
                        const float* __restrict__ Wp_w, const float* __restrict__ Wp_b,
                        const float* __restrict__ Wc_w, const float* __restrict__ Wc_b,
                        const float* __restrict__ Wep_w, const float* __restrict__ Wep_b,
                        const float* __restrict__ Wf_w, const float* __restrict__ Wf_b,
                        unsigned short* __restrict__ xs){
    int pos = blockIdx.x;
    int row = perm[pos];
    unsigned short* xr = xs + (size_t)pos * D_IN;
    int tid = threadIdx.x;
    if (row < 0){
        s8v z = {0,0,0,0,0,0,0,0};
        for (int t = tid; t < D_IN/8; t += blockDim.x) *(s8v*)(xr + t*8) = z;
        return;
    }
    int d = desc_idx[row];
    int s = side_flag[row];
    __shared__ int pidx[64];
    if (tid < 64) pidx[tid] = piece_idx[row*64 + tid];
    __syncthreads();
    const float* Wp  = s ? Wp_b  : Wp_w;
    const float* Wc  = s ? Wc_b  : Wc_w;
    const float* Wep = s ? Wep_b : Wep_w;
    const float* Wf  = s ? Wf_b  : Wf_w;
    int ep  = ep_file[row];
    int epc = ep > 0 ? ep : 0;
    float a = fifty_a[row];
    for (int t = tid; t < D_IN/8; t += blockDim.x){
        int i0 = t*8;
        float v[8];
        if (i0 < 2048){
            int sq = i0 >> 5, c0 = i0 & 31;
            int pc = pidx[sq];
            float msk = pc >= 0 ? 1.0f : 0.0f;
            int pcc = pc > 0 ? pc : 0;
            const float* base = Wp + (((size_t)d*64 + sq)*12 + pcc)*32 + c0;
            float4 a0 = *(const float4*)base;
            float4 a1 = *(const float4*)(base + 4);
            v[0]=a0.x*msk; v[1]=a0.y*msk; v[2]=a0.z*msk; v[3]=a0.w*msk;
            v[4]=a1.x*msk; v[5]=a1.y*msk; v[6]=a1.z*msk; v[7]=a1.w*msk;
        } else if (i0 < 2176){
            int j = i0 - 2048; int ci = j >> 5, c0 = j & 31;
            float cv = castle_ms[row*4 + ci];
            const float* base = Wc + ((size_t)d*4 + ci)*32 + c0;
            float4 a0 = *(const float4*)base;
            float4 a1 = *(const float4*)(base + 4);
            v[0]=a0.x*cv; v[1]=a0.y*cv; v[2]=a0.z*cv; v[3]=a0.w*cv;
            v[4]=a1.x*cv; v[5]=a1.y*cv; v[6]=a1.z*cv; v[7]=a1.w*cv;
        } else if (i0 < 2208){
            int c0 = i0 - 2176;
            float msk = ep >= 0 ? 1.0f : 0.0f;
            const float* base = Wep + ((size_t)d*8 + epc)*32 + c0;
            float4 a0 = *(const float4*)base;
            float4 a1 = *(const float4*)(base + 4);
            v[0]=a0.x*msk; v[1]=a0.y*msk; v[2]=a0.z*msk; v[3]=a0.w*msk;
            v[4]=a1.x*msk; v[5]=a1.y*msk; v[6]=a1.z*msk; v[7]=a1.w*msk;
        } else {
            int c0 = i0 - 2208;
            #pragma unroll
            for (int j = 0; j < 8; j++)
                v[j] = (1.0f - a) * Wf[(size_t)d*64 + c0 + j] + a * Wf[(size_t)d*64 + 32 + c0 + j];
        }
        s8v p;
        #pragma unroll
        for (int j = 0; j < 8; j++) p[j] = (short)f2bf(v[j]);
        *(s8v*)(xr + i0) = p;
    }
}

// ------- fc1 MFMA: groups of 128 rows x 256 cols, K split 4, partial f32 out -------
__launch_bounds__(256)
__global__ void k_fc1(const int4* __restrict__ garr, const int* __restrict__ ngroups,
                      const unsigned short* __restrict__ xs,
                      const unsigned short* __restrict__ Wt,
                      float* __restrict__ h1p){
    int g = blockIdx.x;
    if (g >= *ngroups) return;
    int4 gi = garr[g];
    int tile0 = gi.x, e = gi.y, nv = gi.z;
    int kc = blockIdx.y, nh = blockIdx.z;
    int kstart = (kc <= 2) ? kc*18 : 53;
    int nsteps = (kc < 2) ? 18 : 17;
    int lane = threadIdx.x & 63, wave = threadIdx.x >> 6;
    int quad = lane >> 4, l16 = lane & 15;
    int col0 = nh*128 + wave*32 + l16;
    const unsigned short* Ab = xs + (size_t)(tile0*MT + l16)*D_IN + quad*8;
    const unsigned short* B0 = Wt + ((size_t)e*H1 + col0)*D_IN + quad*8;
    const unsigned short* B1 = B0 + (size_t)16*D_IN;
    f4v acc[8][2];
    #pragma unroll
    for (int mt = 0; mt < 8; mt++){ acc[mt][0] = (f4v){0.f,0.f,0.f,0.f}; acc[mt][1] = (f4v){0.f,0.f,0.f,0.f}; }
    int kend = kstart + nsteps;
    #pragma unroll 2
    for (int s = kstart; s < kend; s++){
        int ko = s*32;
        s8v b0 = *(const s8v*)(B0 + ko);
        s8v b1 = *(const s8v*)(B1 + ko);
        #pragma unroll
        for (int mt = 0; mt < 8; mt++){
            s8v av = *(const s8v*)(Ab + (size_t)mt*MT*D_IN + ko);
            acc[mt][0] = __builtin_amdgcn_mfma_f32_16x16x32_bf16(av, b0, acc[mt][0], 0, 0, 0);
            acc[mt][1] = __builtin_amdgcn_mfma_f32_16x16x32_bf16(av, b1, acc[mt][1], 0, 0, 0);
        }
    }
    float* out = h1p + (size_t)kc*NROWS*H1;
    #pragma unroll
    for (int mt = 0; mt < 8; mt++){
        if (mt >= nv) break;
        int posb = (tile0 + mt)*MT + quad*4;
        #pragma unroll
        for (int r = 0; r < 4; r++){
            out[(size_t)(posb + r)*H1 + col0]      = acc[mt][0][r];
            out[(size_t)(posb + r)*H1 + col0 + 16] = acc[mt][1][r];
        }
    }
}

// ------- fc2: sum K-partials + bias + gelu + LN1, then [16x256]@[256x32] + gelu + LN2 -------
__launch_bounds__(512)
__global__ void k_fc2(const int* __restrict__ tile_e,
                      const float* __restrict__ h1p,
                      const float* __restrict__ b1,
                      const float* __restrict__ g1, const float* __restrict__ be1,
                      const float* __restrict__ W2, const float* __restrict__ b2,
                      const float* __restrict__ g2, const float* __restrict__ be2,
                      float* __restrict__ h){
    int t = blockIdx.x;
    int e = tile_e[t];
    if (e < 0) return;
    __shared__ float sh[MT][H1+1];
    __shared__ float sW[H1*H2];
    __shared__ float sg[H1], sb[H1];
    int tid = threadIdx.x;
    const float4* Wsrc = (const float4*)(W2 + (size_t)e*H1*H2);
    for (int i = tid; i < H1*H2/4; i += 512) ((float4*)sW)[i] = Wsrc[i];
    if (tid < H1){ sg[tid] = g1[e*H1 + tid]; sb[tid] = be1[e*H1 + tid]; }
    for (int slot = tid; slot < MT*H1/4; slot += 512){
        int r = slot >> 6, c4 = (slot & 63) << 2;
        float4 sacc = {0.f,0.f,0.f,0.f};
        #pragma unroll
        for (int kc = 0; kc < KSPLIT; kc++){
            float4 v = *(const float4*)(h1p + ((size_t)kc*NROWS + t*MT + r)*H1 + c4);
            sacc.x += v.x; sacc.y += v.y; sacc.z += v.z; sacc.w += v.w;
        }
        float4 bb = *(const float4*)(b1 + e*H1 + c4);
        sh[r][c4]   = gelu(sacc.x + bb.x);
        sh[r][c4+1] = gelu(sacc.y + bb.y);
        sh[r][c4+2] = gelu(sacc.z + bb.z);
        sh[r][c4+3] = gelu(sacc.w + bb.w);
    }
    __syncthreads();
    int m = tid >> 5, c = tid & 31;
    float s = 0.f;
    for (int k = c; k < H1; k += 32) s += sh[m][k];
    for (int o = 16; o > 0; o >>= 1) s += __shfl_xor(s, o);
    float mean = s * (1.0f/H1);
    float v2 = 0.f;
    for (int k = c; k < H1; k += 32){ float d = sh[m][k] - mean; v2 += d*d; }
    for (int o = 16; o > 0; o >>= 1) v2 += __shfl_xor(v2, o);
    float rs = rsqrtf(v2 * (1.0f/H1) + 1e-5f);
    for (int k = c; k < H1; k += 32)
        sh[m][k] = (sh[m][k] - mean) * rs * sg[k] + sb[k];
    __syncthreads();
    float acc = b2[e*H2 + c];
    #pragma unroll 8
    for (int k = 0; k < H1; k++) acc = fmaf(sh[m][k], sW[k*H2 + c], acc);
    float y = gelu(acc);
    float ss = y;
    for (int o = 16; o > 0; o >>= 1) ss += __shfl_xor(ss, o);
    float mean2 = ss * (1.0f/H2);
    float dv = y - mean2;
    float vv = dv*dv;
    for (int o = 16; o > 0; o >>= 1) vv += __shfl_xor(vv, o);
    float var2 = vv * (1.0f/H2);
    float outv = dv * rsqrtf(var2 + 1e-5f) * g2[e*H2+c] + be2[e*H2+c];
    h[(size_t)(t*MT + m)*H2 + c] = outv;
}

// ---------------- 12 fused residual blocks ----------------
__launch_bounds__(512)
__global__ void k_blocks(const int* __restrict__ tile_e,
                         const float* __restrict__ Aw, const float* __restrict__ Ab,
                         const float* __restrict__ Ag, const float* __restrict__ Abe,
                         const float* __restrict__ Bw, const float* __restrict__ Bb,
                         const float* __restrict__ Bg, const float* __restrict__ Bbe,
                         float* __restrict__ h){
    int t = blockIdx.x;
    int e = tile_e[t];
    if (e < 0) return;
    int m = threadIdx.x >> 5, c = threadIdx.x & 31;
    int pos = t*MT + m;
    float hv = h[(size_t)pos*H2 + c];
    __shared__ float sA[1024], sB[1024], shh[MT][33];
    for (int tb = 0; tb < NBLK; tb++){
        const float* A = Aw + ((size_t)tb*E + e)*1024;
        const float* B = Bw + ((size_t)tb*E + e)*1024;
        __syncthreads();
        for (int i = threadIdx.x; i < 1024; i += 512){ sA[i] = A[i]; sB[i] = B[i]; }
        shh[m][c] = hv;
        __syncthreads();
        float acc = Ab[((size_t)tb*E + e)*32 + c];
        #pragma unroll
        for (int k = 0; k < 32; k++) acc = fmaf(shh[m][k], sA[k*32 + c], acc);
        float y = gelu(acc);
        float s = y;
        for (int o = 16; o > 0; o >>= 1) s += __shfl_xor(s, o);
        float mean = s * (1.0f/32);
        float dv = y - mean;
        float v = dv*dv;
        for (int o = 16; o > 0; o >>= 1) v += __shfl_xor(v, o);
        float var = v * (1.0f/32);
        y = dv * rsqrtf(var + 1e-5f) * Ag[((size_t)tb*E+e)*32+c] + Abe[((size_t)tb*E+e)*32+c];
        __syncthreads();
        shh[m][c] = y;
        __syncthreads();
        acc = Bb[((size_t)tb*E + e)*32 + c];
        #pragma unroll
        for (int k = 0; k < 32; k++) acc = fmaf(shh[m][k], sB[k*32 + c], acc);
        y = gelu(acc);
        s = y;
        for (int o = 16; o > 0; o >>= 1) s += __shfl_xor(s, o);
        mean = s * (1.0f/32);
        dv = y - mean;
        v = dv*dv;
        for (int o = 16; o > 0; o >>= 1) v += __shfl_xor(v, o);
        var = v * (1.0f/32);
        y = dv * rsqrtf(var + 1e-5f) * Bg[((size_t)tb*E+e)*32+c] + Bbe[((size_t)tb*E+e)*32+c];
        hv += y;
    }
    h[(size_t)pos*H2 + c] = hv;
}

// ---------------- out proj + softmax + p_win (one wave per row) ----------------
__global__ void k_out(const int* __restrict__ perm, const int* __restrict__ tile_e,
                      const float* __restrict__ h,
                      const float* __restrict__ Ow, const float* __restrict__ Ob,
                      const float* __restrict__ bins,
                      float* __restrict__ out){
    int wid = threadIdx.x >> 6, lane = threadIdx.x & 63;
    int pos = blockIdx.x*4 + wid;
    if (pos >= NPAD) return;
    int row = perm[pos];
    if (row < 0) return;
    int e = tile_e[pos / MT];
    float gv = 0.0f;
    if (lane < 32) gv = gelu(h[(size_t)pos*H2 + lane]);
    float acc = (lane < NOUT) ? Ob[e*NOUT + lane] : -INFINITY;
    const float* W = Ow + (size_t)e*32*NOUT;
    #pragma unroll
    for (int k = 0; k < 32; k++){
        float gk = __shfl(gv, k);
        if (lane < NOUT) acc = fmaf(gk, W[k*NOUT + lane], acc);
    }
    if (lane < NOUT) out[(size_t)row*NOUT + lane] = acc;
    float mx = acc;
    for (int o = 32; o > 0; o >>= 1) mx = fmaxf(mx, __shfl_xor(mx, o));
    float p = (lane < NOUT) ? expf(acc - mx) : 0.0f;
    float sum = p;
    for (int o = 32; o > 0; o >>= 1) sum += __shfl_xor(sum, o);
    float pb = (lane < NOUT) ? p * bins[lane] : 0.0f;
    float sb = pb;
    for (int o = 32; o > 0; o >>= 1) sb += __shfl_xor(sb, o);
    if (lane == 0) out[(size_t)N*NOUT + row] = sb / sum;
}

extern "C" void kernel_launch(void* const* d_in, const int* in_sizes, int n_in,
                              void* d_out, int out_size, void* d_ws, size_t ws_size,
                              hipStream_t stream){
    const int*   piece_idx = (const int*)d_in[0];
    const int*   side_flag = (const int*)d_in[1];
    const int*   ep_file   = (const int*)d_in[2];
    const float* castle_ms = (const float*)d_in[3];
    const float* fifty_a   = (const float*)d_in[4];
    const int*   desc      = (const int*)d_in[5];
    const float* Wp_w  = (const float*)d_in[6];
    const float* Wp_b  = (const float*)d_in[7];
    const float* Wc_w  = (const float*)d_in[8];
    const float* Wc_b  = (const float*)d_in[9];
    const float* Wep_w = (const float*)d_in[10];
    const float* Wep_b = (const float*)d_in[11];
    const float* Wf_w  = (const float*)d_in[12];
    const float* Wf_b  = (const float*)d_in[13];
    const float* fc1_w = (const float*)d_in[14];
    const float* fc1_b = (const float*)d_in[15];
    const float* ln1_g = (const float*)d_in[16];
    const float* ln1_b = (const float*)d_in[17];
    const float* fc2_w = (const float*)d_in[18];
    const float* fc2_b = (const float*)d_in[19];
    const float* ln2_g = (const float*)d_in[20];
    const float* ln2_b = (const float*)d_in[21];
    const float* blkA_w  = (const float*)d_in[22];
    const float* blkA_b  = (const float*)d_in[23];
    const float* blkA_g  = (const float*)d_in[24];
    const float* blkA_be = (const float*)d_in[25];
    const float* blkB_w  = (const float*)d_in[26];
    const float* blkB_b  = (const float*)d_in[27];
    const float* blkB_g  = (const float*)d_in[28];
    const float* blkB_be = (const float*)d_in[29];
    const float* out_w = (const float*)d_in[30];
    const float* out_b = (const float*)d_in[31];
    const float* bins  = (const float*)d_in[32];

    char* wsp = (char*)d_ws;
    auto alloc = [&](size_t bytes){ void* p = (void*)wsp; wsp += (bytes + 255) & ~(size_t)255; return p; };
    int*            perm    = (int*)            alloc((size_t)NPAD*4);
    int*            tile_e  = (int*)            alloc((size_t)NTILE*4);
    int4*           garr    = (int4*)           alloc((size_t)GMAX*16);
    int*            ngroups = (int*)            alloc(256);
    unsigned short* Wt      = (unsigned short*) alloc((size_t)E*H1*D_IN*2);
    unsigned short* xs      = (unsigned short*) alloc((size_t)(NPAD+128)*D_IN*2);
    float*          h1p     = (float*)          alloc((size_t)KSPLIT*NROWS*H1*4);
    float*          h       = (float*)          alloc((size_t)NPAD*H2*4);

    k_sort<<<1, 256, 0, stream>>>(desc, perm, tile_e, garr, ngroups);
    k_convert<<<dim3(D_IN/64, H1/64, E), 256, 0, stream>>>(fc1_w, Wt);
    k_build<<<NPAD, 256, 0, stream>>>(perm, piece_idx, side_flag, ep_file, castle_ms,
                                      fifty_a, desc, Wp_w, Wp_b, Wc_w, Wc_b,
                                      Wep_w, Wep_b, Wf_w, Wf_b, xs);
    k_fc1<<<dim3(GMAX, KSPLIT, 2), 256, 0, stream>>>(garr, ngroups, xs, Wt, h1p);
    k_fc2<<<NTILE, 512, 0, stream>>>(tile_e, h1p, fc1_b, ln1_g, ln1_b,
                                     fc2_w, fc2_b, ln2_g, ln2_b, h);
    k_blocks<<<NTILE, 512, 0, stream>>>(tile_e, blkA_w, blkA_b, blkA_g, blkA_be,
                                        blkB_w, blkB_b, blkB_g, blkB_be, h);
    k_out<<<(NPAD + 3)/4, 256, 0, stream>>>(perm, tile_e, h, out_w, out_b, bins, (float*)d_out);
}